// Round 1
// baseline (387.508 us; speedup 1.0000x reference)
//
#include <hip/hip_runtime.h>
#include <stdint.h>

#define HD 128
#define EPS 1e-5f

// ---------------- CSR build ----------------
__global__ void k_hist_dst(const int* __restrict__ dst, int* __restrict__ cnt, int E) {
  int i = blockIdx.x * blockDim.x + threadIdx.x;
  int stride = gridDim.x * blockDim.x;
  for (; i < E; i += stride) atomicAdd(&cnt[dst[i]], 1);
}

__global__ void k_dinv(const int* __restrict__ cnt, float* __restrict__ dinv, int N) {
  int i = blockIdx.x * blockDim.x + threadIdx.x;
  if (i < N) dinv[i] = rsqrtf((float)cnt[i] + 1.0f);  // +1 self-loop; always > 0
}

__global__ __launch_bounds__(256) void k_scan1(const int* __restrict__ cnt, int* __restrict__ rowptr,
                                               int* __restrict__ bsums, int N) {
  __shared__ int lds[256];
  const int t = threadIdx.x;
  int base = blockIdx.x * 2048 + t * 8;
  int v[8]; int s = 0;
#pragma unroll
  for (int i = 0; i < 8; ++i) { int idx = base + i; v[i] = (idx < N) ? cnt[idx] : 0; s += v[i]; }
  lds[t] = s; __syncthreads();
  for (int off = 1; off < 256; off <<= 1) {
    int tv = (t >= off) ? lds[t - off] : 0;
    __syncthreads();
    lds[t] += tv;
    __syncthreads();
  }
  if (t == 255) bsums[blockIdx.x] = lds[255];
  int run = lds[t] - s;  // exclusive prefix for this thread's chunk
#pragma unroll
  for (int i = 0; i < 8; ++i) { int idx = base + i; if (idx < N) rowptr[idx] = run; run += v[i]; }
}

__global__ __launch_bounds__(256) void k_scan2(int* __restrict__ bsums, int nb) {
  __shared__ int lds[256];
  const int t = threadIdx.x;
  int v = (t < nb) ? bsums[t] : 0;
  lds[t] = v; __syncthreads();
  for (int off = 1; off < 256; off <<= 1) {
    int tv = (t >= off) ? lds[t - off] : 0;
    __syncthreads();
    lds[t] += tv;
    __syncthreads();
  }
  if (t < nb) bsums[t] = lds[t] - v;  // exclusive
}

__global__ void k_scan3(int* __restrict__ rowptr, const int* __restrict__ bsums, int N, int E) {
  int i = blockIdx.x * blockDim.x + threadIdx.x;
  if (i < N) rowptr[i] += bsums[i >> 11];
  else if (i == N) rowptr[N] = E;
}

__global__ void k_scatter(const int* __restrict__ src, const int* __restrict__ dst,
                          const int* __restrict__ rowptr, int* __restrict__ fill,
                          int* __restrict__ colidx, int E) {
  int i = blockIdx.x * blockDim.x + threadIdx.x;
  int stride = gridDim.x * blockDim.x;
  for (; i < E; i += stride) {
    int d = dst[i];
    int pos = atomicAdd(&fill[d], 1);
    colidx[rowptr[d] + pos] = src[i];
  }
}

// ---------------- GEMM: Y[r] = dinv[r] * (bnrelu?(A[r]) @ W) ----------------
#define SA_LD 132  // pad 128->132: A broadcast reads become 2-way conflicts (free), float4-alignable
__global__ __launch_bounds__(512) void k_gemm(const float* __restrict__ A, const float* __restrict__ W,
                                              float* __restrict__ Y, int N,
                                              const float* __restrict__ dinv,
                                              const float* __restrict__ scale,
                                              const float* __restrict__ shift) {
  __shared__ float sW[HD * HD];      // 64 KB
  __shared__ float sA[128 * SA_LD];  // 66 KB
  const int tid = threadIdx.x;
  const int row0 = blockIdx.x * 128;
  for (int i = tid * 4; i < HD * HD; i += 512 * 4) {
    *(float4*)&sW[i] = *(const float4*)&W[i];
  }
  for (int i = tid * 4; i < 128 * HD; i += 512 * 4) {
    int r = row0 + (i >> 7);
    int c = i & 127;
    float4 v = make_float4(0.f, 0.f, 0.f, 0.f);
    if (r < N) v = *(const float4*)&A[(size_t)r * HD + c];
    if (scale) {  // fused BN+ReLU on the input tile (layer 2)
      v.x = fmaxf(0.f, v.x * scale[c + 0] + shift[c + 0]);
      v.y = fmaxf(0.f, v.y * scale[c + 1] + shift[c + 1]);
      v.z = fmaxf(0.f, v.z * scale[c + 2] + shift[c + 2]);
      v.w = fmaxf(0.f, v.w * scale[c + 3] + shift[c + 3]);
    }
    *(float4*)&sA[(i >> 7) * SA_LD + c] = v;
  }
  __syncthreads();
  const int c0 = (tid & 15) * 4;   // cols c0..c0+3 and c0+64..c0+67
  const int r0 = (tid >> 4) * 4;   // rows r0..r0+3
  float acc[4][8] = {};
#pragma unroll 4
  for (int k = 0; k < HD; ++k) {
    float av[4];
#pragma unroll
    for (int i = 0; i < 4; ++i) av[i] = sA[(r0 + i) * SA_LD + k];
    float4 w0 = *(const float4*)&sW[k * HD + c0];
    float4 w1 = *(const float4*)&sW[k * HD + c0 + 64];
    float wv[8] = {w0.x, w0.y, w0.z, w0.w, w1.x, w1.y, w1.z, w1.w};
#pragma unroll
    for (int i = 0; i < 4; ++i)
#pragma unroll
      for (int j = 0; j < 8; ++j) acc[i][j] = fmaf(av[i], wv[j], acc[i][j]);
  }
  for (int i = 0; i < 4; ++i) {
    int r = row0 + r0 + i;
    if (r >= N) continue;
    float d = dinv[r];
    float4 o0 = make_float4(acc[i][0] * d, acc[i][1] * d, acc[i][2] * d, acc[i][3] * d);
    float4 o1 = make_float4(acc[i][4] * d, acc[i][5] * d, acc[i][6] * d, acc[i][7] * d);
    *(float4*)&Y[(size_t)r * HD + c0] = o0;
    *(float4*)&Y[(size_t)r * HD + c0 + 64] = o1;
  }
}

// ---------------- aggregate: Out[n] = dinv[n]*(Yp[n] + sum_{s in N(n)} Yp[s]) ----------------
__global__ __launch_bounds__(256) void k_aggregate(const float* __restrict__ Yp,
                                                   const int* __restrict__ rowptr,
                                                   const int* __restrict__ colidx,
                                                   const float* __restrict__ dinv,
                                                   float* __restrict__ Out, int N) {
  int n = (blockIdx.x * blockDim.x + threadIdx.x) >> 6;  // one wave per node
  int lane = threadIdx.x & 63;
  if (n >= N) return;
  const int beg = rowptr[n];
  const int end = rowptr[n + 1];
  const int co = lane * 2;
  float2 acc = *(const float2*)&Yp[(size_t)n * HD + co];  // self loop
  int e = beg;
  for (; e + 1 < end; e += 2) {
    int s0 = colidx[e];
    int s1 = colidx[e + 1];
    float2 v0 = *(const float2*)&Yp[(size_t)s0 * HD + co];
    float2 v1 = *(const float2*)&Yp[(size_t)s1 * HD + co];
    acc.x += v0.x + v1.x;
    acc.y += v0.y + v1.y;
  }
  if (e < end) {
    int s0 = colidx[e];
    float2 v0 = *(const float2*)&Yp[(size_t)s0 * HD + co];
    acc.x += v0.x; acc.y += v0.y;
  }
  float dd = dinv[n];
  float2 o; o.x = acc.x * dd; o.y = acc.y * dd;
  *(float2*)&Out[(size_t)n * HD + co] = o;
}

// ---------------- per-column sum / sumsq ----------------
__global__ __launch_bounds__(256) void k_colstats(const float* __restrict__ X, int N,
                                                  float* __restrict__ sums) {
  const int c = threadIdx.x & 127;
  const int half = threadIdx.x >> 7;
  float s = 0.f, q = 0.f;
  for (int r = blockIdx.x * 2 + half; r < N; r += gridDim.x * 2) {
    float v = X[(size_t)r * HD + c];
    s += v; q += v * v;
  }
  __shared__ float ls[256], lq[256];
  ls[threadIdx.x] = s; lq[threadIdx.x] = q;
  __syncthreads();
  if (threadIdx.x < 128) {
    atomicAdd(&sums[c], ls[threadIdx.x] + ls[threadIdx.x + 128]);
    atomicAdd(&sums[128 + c], lq[threadIdx.x] + lq[threadIdx.x + 128]);
  }
}

__global__ void k_bnparams(const float* __restrict__ sums, float invN,
                           const float* __restrict__ gamma, const float* __restrict__ beta,
                           float* __restrict__ scale, float* __restrict__ shift) {
  int c = threadIdx.x;
  if (c < HD) {
    float mean = sums[c] * invN;
    float var = sums[HD + c] * invN - mean * mean;
    float sc = gamma[c] * rsqrtf(var + EPS);
    scale[c] = sc;
    shift[c] = beta[c] - mean * sc;  // note: linear bias b cancels in BN (mean-subtracted)
  }
}

__global__ void k_ghist(const int* __restrict__ batch, int* __restrict__ gcnt, int N) {
  int i = blockIdx.x * blockDim.x + threadIdx.x;
  int stride = gridDim.x * blockDim.x;
  for (; i < N; i += stride) atomicAdd(&gcnt[batch[i]], 1);
}

// ---------------- fused BN2+ReLU+dot(Wout)+pool-scatter ----------------
__global__ __launch_bounds__(256) void k_finalnode(const float* __restrict__ Agg,
                                                   const float* __restrict__ scale,
                                                   const float* __restrict__ shift,
                                                   const float* __restrict__ wout,
                                                   const int* __restrict__ batch,
                                                   float* __restrict__ gsum, int N) {
  int n = (blockIdx.x * blockDim.x + threadIdx.x) >> 6;
  int lane = threadIdx.x & 63;
  if (n >= N) return;
  int c = lane * 2;
  float2 v = *(const float2*)&Agg[(size_t)n * HD + c];
  float h0 = fmaxf(0.f, v.x * scale[c] + shift[c]);
  float h1 = fmaxf(0.f, v.y * scale[c + 1] + shift[c + 1]);
  float p = h0 * wout[c] + h1 * wout[c + 1];
  for (int off = 32; off > 0; off >>= 1) p += __shfl_down(p, off);
  if (lane == 0) atomicAdd(&gsum[batch[n]], p);
}

__global__ void k_finalout(const float* __restrict__ gsum, const int* __restrict__ gcnt,
                           const float* __restrict__ bout, float* __restrict__ out, int G) {
  int g = blockIdx.x * blockDim.x + threadIdx.x;
  if (g < G) out[g] = gsum[g] / fmaxf((float)gcnt[g], 1.0f) + bout[0];
}

extern "C" void kernel_launch(void* const* d_in, const int* in_sizes, int n_in,
                              void* d_out, int out_size, void* d_ws, size_t ws_size,
                              hipStream_t stream) {
  (void)n_in; (void)ws_size;
  const float* x      = (const float*)d_in[0];
  const int*   ei     = (const int*)d_in[1];
  const int*   batch  = (const int*)d_in[2];
  const float* W1     = (const float*)d_in[3];
  const float* gamma1 = (const float*)d_in[5];
  const float* beta1  = (const float*)d_in[6];
  const float* W2     = (const float*)d_in[7];
  const float* gamma2 = (const float*)d_in[9];
  const float* beta2  = (const float*)d_in[10];
  const float* wout   = (const float*)d_in[11];
  const float* bout   = (const float*)d_in[12];
  float* out = (float*)d_out;

  const int N = in_sizes[0] / HD;
  const int E = in_sizes[1] / 2;
  const int G = out_size;
  const int* src = ei;
  const int* dst = ei + E;

  char* p = (char*)d_ws;
  auto carve = [&](size_t bytes) { char* r = p; p += (bytes + 255) & ~(size_t)255; return r; };
  float* bufY   = (float*)carve((size_t)N * HD * 4);
  float* bufAgg = (float*)carve((size_t)N * HD * 4);
  int*   colidx = (int*)carve((size_t)E * 4);
  int*   rowptr = (int*)carve((size_t)(N + 1) * 4);
  float* dinv   = (float*)carve((size_t)N * 4);
  float* scale1 = (float*)carve(HD * 4);
  float* shift1 = (float*)carve(HD * 4);
  float* scale2 = (float*)carve(HD * 4);
  float* shift2 = (float*)carve(HD * 4);
  char* z0 = p;  // ---- zero-initialized region ----
  int*   cnt   = (int*)carve((size_t)N * 4);
  int*   fill  = (int*)carve((size_t)N * 4);
  float* sums1 = (float*)carve(256 * 4);
  float* sums2 = (float*)carve(256 * 4);
  float* gsum  = (float*)carve((size_t)G * 4);
  int*   gcnt  = (int*)carve((size_t)G * 4);
  int*   bsums = (int*)carve(256 * 4);
  size_t zbytes = (size_t)(p - z0);

  hipMemsetAsync(z0, 0, zbytes, stream);

  // CSR build (shared by both conv layers)
  k_hist_dst<<<256, 256, 0, stream>>>(dst, cnt, E);
  k_dinv<<<(N + 255) / 256, 256, 0, stream>>>(cnt, dinv, N);
  int nb = (N + 2047) / 2048;
  k_scan1<<<nb, 256, 0, stream>>>(cnt, rowptr, bsums, N);
  k_scan2<<<1, 256, 0, stream>>>(bsums, nb);
  k_scan3<<<(N + 1 + 255) / 256, 256, 0, stream>>>(rowptr, bsums, N, E);
  k_scatter<<<256, 256, 0, stream>>>(src, dst, rowptr, fill, colidx, E);

  int gblocks = (N + 127) / 128;
  int ablocks = (N + 3) / 4;
  // layer 1
  k_gemm<<<gblocks, 512, 0, stream>>>(x, W1, bufY, N, dinv, nullptr, nullptr);
  k_aggregate<<<ablocks, 256, 0, stream>>>(bufY, rowptr, colidx, dinv, bufAgg, N);
  k_colstats<<<512, 256, 0, stream>>>(bufAgg, N, sums1);
  k_bnparams<<<1, 128, 0, stream>>>(sums1, 1.0f / (float)N, gamma1, beta1, scale1, shift1);
  // layer 2 (BN1+ReLU fused into GEMM2 input staging)
  k_gemm<<<gblocks, 512, 0, stream>>>(bufAgg, W2, bufY, N, dinv, scale1, shift1);
  k_aggregate<<<ablocks, 256, 0, stream>>>(bufY, rowptr, colidx, dinv, bufAgg, N);
  k_colstats<<<512, 256, 0, stream>>>(bufAgg, N, sums2);
  k_bnparams<<<1, 128, 0, stream>>>(sums2, 1.0f / (float)N, gamma2, beta2, scale2, shift2);
  // pooling + output head (BN2+ReLU+proj fused, h2 never materialized)
  k_ghist<<<256, 256, 0, stream>>>(batch, gcnt, N);
  k_finalnode<<<ablocks, 256, 0, stream>>>(bufAgg, scale2, shift2, wout, batch, gsum, N);
  k_finalout<<<(G + 255) / 256, 256, 0, stream>>>(gsum, gcnt, bout, out, G);
}

// Round 2
// 342.814 us; speedup vs baseline: 1.1304x; 1.1304x over previous
//
#include <hip/hip_runtime.h>
#include <stdint.h>

#define HD 128
#define EPS 1e-5f

// bf16 pack/unpack (RNE), explicit bit layout: low ushort = even col.
__device__ inline unsigned bf_round(float f) {
  unsigned u = __float_as_uint(f);
  return (u + 0x7fffu + ((u >> 16) & 1u)) >> 16;
}
__device__ inline unsigned bf_pack2(float x, float y) {
  return bf_round(x) | (bf_round(y) << 16);
}
__device__ inline float2 bf_unpack2(unsigned u) {
  float2 r;
  r.x = __uint_as_float(u << 16);
  r.y = __uint_as_float(u & 0xffff0000u);
  return r;
}

// ---------------- CSR build ----------------
__global__ void k_hist_dst(const int* __restrict__ dst, int* __restrict__ cnt, int E) {
  int i = blockIdx.x * blockDim.x + threadIdx.x;
  int stride = gridDim.x * blockDim.x;
  for (; i < E; i += stride) atomicAdd(&cnt[dst[i]], 1);
}

__global__ void k_dinv(const int* __restrict__ cnt, float* __restrict__ dinv, int N) {
  int i = blockIdx.x * blockDim.x + threadIdx.x;
  if (i < N) dinv[i] = rsqrtf((float)cnt[i] + 1.0f);  // +1 self-loop; always > 0
}

__global__ __launch_bounds__(256) void k_scan1(const int* __restrict__ cnt, int* __restrict__ rowptr,
                                               int* __restrict__ bsums, int N) {
  __shared__ int lds[256];
  const int t = threadIdx.x;
  int base = blockIdx.x * 2048 + t * 8;
  int v[8]; int s = 0;
#pragma unroll
  for (int i = 0; i < 8; ++i) { int idx = base + i; v[i] = (idx < N) ? cnt[idx] : 0; s += v[i]; }
  lds[t] = s; __syncthreads();
  for (int off = 1; off < 256; off <<= 1) {
    int tv = (t >= off) ? lds[t - off] : 0;
    __syncthreads();
    lds[t] += tv;
    __syncthreads();
  }
  if (t == 255) bsums[blockIdx.x] = lds[255];
  int run = lds[t] - s;  // exclusive prefix for this thread's chunk
#pragma unroll
  for (int i = 0; i < 8; ++i) { int idx = base + i; if (idx < N) rowptr[idx] = run; run += v[i]; }
}

__global__ __launch_bounds__(256) void k_scan2(int* __restrict__ bsums, int nb) {
  __shared__ int lds[256];
  const int t = threadIdx.x;
  int v = (t < nb) ? bsums[t] : 0;
  lds[t] = v; __syncthreads();
  for (int off = 1; off < 256; off <<= 1) {
    int tv = (t >= off) ? lds[t - off] : 0;
    __syncthreads();
    lds[t] += tv;
    __syncthreads();
  }
  if (t < nb) bsums[t] = lds[t] - v;  // exclusive
}

__global__ void k_scan3(int* __restrict__ rowptr, const int* __restrict__ bsums, int N, int E) {
  int i = blockIdx.x * blockDim.x + threadIdx.x;
  if (i < N) rowptr[i] += bsums[i >> 11];
  else if (i == N) rowptr[N] = E;
}

__global__ void k_scatter(const int* __restrict__ src, const int* __restrict__ dst,
                          const int* __restrict__ rowptr, int* __restrict__ fill,
                          int* __restrict__ colidx, int E) {
  int i = blockIdx.x * blockDim.x + threadIdx.x;
  int stride = gridDim.x * blockDim.x;
  for (; i < E; i += stride) {
    int d = dst[i];
    int pos = atomicAdd(&fill[d], 1);
    colidx[rowptr[d] + pos] = src[i];
  }
}

// ---------------- GEMM: Yp[r] = bf16( dinv[r] * (bnrelu?(A[r]) @ W) ) ----------------
#define SA_LD 132  // pad 128->132: A broadcast reads become 2-way conflicts (free), float4-alignable
__global__ __launch_bounds__(512) void k_gemm(const float* __restrict__ A, const float* __restrict__ W,
                                              unsigned* __restrict__ Yp, int N,
                                              const float* __restrict__ dinv,
                                              const float* __restrict__ scale,
                                              const float* __restrict__ shift) {
  __shared__ float sW[HD * HD];      // 64 KB
  __shared__ float sA[128 * SA_LD];  // 66 KB
  const int tid = threadIdx.x;
  const int row0 = blockIdx.x * 128;
  for (int i = tid * 4; i < HD * HD; i += 512 * 4) {
    *(float4*)&sW[i] = *(const float4*)&W[i];
  }
  for (int i = tid * 4; i < 128 * HD; i += 512 * 4) {
    int r = row0 + (i >> 7);
    int c = i & 127;
    float4 v = make_float4(0.f, 0.f, 0.f, 0.f);
    if (r < N) v = *(const float4*)&A[(size_t)r * HD + c];
    if (scale) {  // fused BN+ReLU on the input tile (layer 2)
      v.x = fmaxf(0.f, v.x * scale[c + 0] + shift[c + 0]);
      v.y = fmaxf(0.f, v.y * scale[c + 1] + shift[c + 1]);
      v.z = fmaxf(0.f, v.z * scale[c + 2] + shift[c + 2]);
      v.w = fmaxf(0.f, v.w * scale[c + 3] + shift[c + 3]);
    }
    *(float4*)&sA[(i >> 7) * SA_LD + c] = v;
  }
  __syncthreads();
  const int c0 = (tid & 15) * 4;   // cols c0..c0+3 and c0+64..c0+67
  const int r0 = (tid >> 4) * 4;   // rows r0..r0+3
  float acc[4][8] = {};
#pragma unroll 4
  for (int k = 0; k < HD; ++k) {
    float av[4];
#pragma unroll
    for (int i = 0; i < 4; ++i) av[i] = sA[(r0 + i) * SA_LD + k];
    float4 w0 = *(const float4*)&sW[k * HD + c0];
    float4 w1 = *(const float4*)&sW[k * HD + c0 + 64];
    float wv[8] = {w0.x, w0.y, w0.z, w0.w, w1.x, w1.y, w1.z, w1.w};
#pragma unroll
    for (int i = 0; i < 4; ++i)
#pragma unroll
      for (int j = 0; j < 8; ++j) acc[i][j] = fmaf(av[i], wv[j], acc[i][j]);
  }
  for (int i = 0; i < 4; ++i) {
    int r = row0 + r0 + i;
    if (r >= N) continue;
    float d = dinv[r];
    uint2 p0, p1;
    p0.x = bf_pack2(acc[i][0] * d, acc[i][1] * d);
    p0.y = bf_pack2(acc[i][2] * d, acc[i][3] * d);
    p1.x = bf_pack2(acc[i][4] * d, acc[i][5] * d);
    p1.y = bf_pack2(acc[i][6] * d, acc[i][7] * d);
    *(uint2*)&Yp[(size_t)r * 64 + (c0 >> 1)] = p0;
    *(uint2*)&Yp[(size_t)r * 64 + ((c0 + 64) >> 1)] = p1;
  }
}

// ---------------- aggregate: Out[n] = dinv[n]*(Yp[n] + sum_{s in N(n)} Yp[s]) ----------------
// One wave per node; lane owns cols (2*lane, 2*lane+1) as one packed uint per row.
// Neighbor list loaded cooperatively (1 coalesced load) + shfl broadcast; gather unrolled x4.
__global__ __launch_bounds__(256) void k_aggregate(const unsigned* __restrict__ Yp,
                                                   const int* __restrict__ rowptr,
                                                   const int* __restrict__ colidx,
                                                   const float* __restrict__ dinv,
                                                   float* __restrict__ Out, int N) {
  int n = (blockIdx.x * blockDim.x + threadIdx.x) >> 6;  // one wave per node
  int lane = threadIdx.x & 63;
  if (n >= N) return;
  const int beg = rowptr[n];
  const int deg = rowptr[n + 1] - beg;
  const int m = deg < 64 ? deg : 64;
  int nbr = (lane < deg) ? colidx[beg + lane] : 0;
  float2 self = bf_unpack2(Yp[(size_t)n * 64 + lane]);
  float ax = self.x, ay = self.y;
  int j = 0;
  for (; j + 4 <= m; j += 4) {
    int s0 = __shfl(nbr, j, 64);
    int s1 = __shfl(nbr, j + 1, 64);
    int s2 = __shfl(nbr, j + 2, 64);
    int s3 = __shfl(nbr, j + 3, 64);
    unsigned u0 = Yp[(size_t)s0 * 64 + lane];
    unsigned u1 = Yp[(size_t)s1 * 64 + lane];
    unsigned u2 = Yp[(size_t)s2 * 64 + lane];
    unsigned u3 = Yp[(size_t)s3 * 64 + lane];
    float2 v0 = bf_unpack2(u0), v1 = bf_unpack2(u1);
    float2 v2 = bf_unpack2(u2), v3 = bf_unpack2(u3);
    ax += (v0.x + v1.x) + (v2.x + v3.x);
    ay += (v0.y + v1.y) + (v2.y + v3.y);
  }
  for (; j < m; ++j) {
    int s0 = __shfl(nbr, j, 64);
    float2 v0 = bf_unpack2(Yp[(size_t)s0 * 64 + lane]);
    ax += v0.x; ay += v0.y;
  }
  // rare tail: degree > 64
  for (int e = beg + 64; e < beg + deg; ++e) {
    float2 v0 = bf_unpack2(Yp[(size_t)colidx[e] * 64 + lane]);
    ax += v0.x; ay += v0.y;
  }
  float dd = dinv[n];
  float2 o; o.x = ax * dd; o.y = ay * dd;
  *(float2*)&Out[(size_t)n * HD + lane * 2] = o;
}

// ---------------- per-column sum / sumsq ----------------
__global__ __launch_bounds__(256) void k_colstats(const float* __restrict__ X, int N,
                                                  float* __restrict__ sums) {
  const int c = threadIdx.x & 127;
  const int half = threadIdx.x >> 7;
  float s = 0.f, q = 0.f;
  for (int r = blockIdx.x * 2 + half; r < N; r += gridDim.x * 2) {
    float v = X[(size_t)r * HD + c];
    s += v; q += v * v;
  }
  __shared__ float ls[256], lq[256];
  ls[threadIdx.x] = s; lq[threadIdx.x] = q;
  __syncthreads();
  if (threadIdx.x < 128) {
    atomicAdd(&sums[c], ls[threadIdx.x] + ls[threadIdx.x + 128]);
    atomicAdd(&sums[128 + c], lq[threadIdx.x] + lq[threadIdx.x + 128]);
  }
}

__global__ void k_bnparams(const float* __restrict__ sums, float invN,
                           const float* __restrict__ gamma, const float* __restrict__ beta,
                           float* __restrict__ scale, float* __restrict__ shift) {
  int c = threadIdx.x;
  if (c < HD) {
    float mean = sums[c] * invN;
    float var = sums[HD + c] * invN - mean * mean;
    float sc = gamma[c] * rsqrtf(var + EPS);
    scale[c] = sc;
    shift[c] = beta[c] - mean * sc;  // note: linear bias b cancels in BN (mean-subtracted)
  }
}

__global__ void k_ghist(const int* __restrict__ batch, int* __restrict__ gcnt, int N) {
  int i = blockIdx.x * blockDim.x + threadIdx.x;
  int stride = gridDim.x * blockDim.x;
  for (; i < N; i += stride) atomicAdd(&gcnt[batch[i]], 1);
}

// ---------------- fused BN2+ReLU+dot(Wout)+pool-scatter ----------------
__global__ __launch_bounds__(256) void k_finalnode(const float* __restrict__ Agg,
                                                   const float* __restrict__ scale,
                                                   const float* __restrict__ shift,
                                                   const float* __restrict__ wout,
                                                   const int* __restrict__ batch,
                                                   float* __restrict__ gsum, int N) {
  int n = (blockIdx.x * blockDim.x + threadIdx.x) >> 6;
  int lane = threadIdx.x & 63;
  if (n >= N) return;
  int c = lane * 2;
  float2 v = *(const float2*)&Agg[(size_t)n * HD + c];
  float h0 = fmaxf(0.f, v.x * scale[c] + shift[c]);
  float h1 = fmaxf(0.f, v.y * scale[c + 1] + shift[c + 1]);
  float p = h0 * wout[c] + h1 * wout[c + 1];
  for (int off = 32; off > 0; off >>= 1) p += __shfl_down(p, off);
  if (lane == 0) atomicAdd(&gsum[batch[n]], p);
}

__global__ void k_finalout(const float* __restrict__ gsum, const int* __restrict__ gcnt,
                           const float* __restrict__ bout, float* __restrict__ out, int G) {
  int g = blockIdx.x * blockDim.x + threadIdx.x;
  if (g < G) out[g] = gsum[g] / fmaxf((float)gcnt[g], 1.0f) + bout[0];
}

extern "C" void kernel_launch(void* const* d_in, const int* in_sizes, int n_in,
                              void* d_out, int out_size, void* d_ws, size_t ws_size,
                              hipStream_t stream) {
  (void)n_in; (void)ws_size;
  const float* x      = (const float*)d_in[0];
  const int*   ei     = (const int*)d_in[1];
  const int*   batch  = (const int*)d_in[2];
  const float* W1     = (const float*)d_in[3];
  const float* gamma1 = (const float*)d_in[5];
  const float* beta1  = (const float*)d_in[6];
  const float* W2     = (const float*)d_in[7];
  const float* gamma2 = (const float*)d_in[9];
  const float* beta2  = (const float*)d_in[10];
  const float* wout   = (const float*)d_in[11];
  const float* bout   = (const float*)d_in[12];
  float* out = (float*)d_out;

  const int N = in_sizes[0] / HD;
  const int E = in_sizes[1] / 2;
  const int G = out_size;
  const int* src = ei;
  const int* dst = ei + E;

  char* p = (char*)d_ws;
  auto carve = [&](size_t bytes) { char* r = p; p += (bytes + 255) & ~(size_t)255; return r; };
  unsigned* bufY = (unsigned*)carve((size_t)N * 64 * 4);   // bf16-packed Y' [N,128]
  float* bufAgg  = (float*)carve((size_t)N * HD * 4);
  int*   colidx  = (int*)carve((size_t)E * 4);
  int*   rowptr  = (int*)carve((size_t)(N + 1) * 4);
  float* dinv    = (float*)carve((size_t)N * 4);
  float* scale1  = (float*)carve(HD * 4);
  float* shift1  = (float*)carve(HD * 4);
  float* scale2  = (float*)carve(HD * 4);
  float* shift2  = (float*)carve(HD * 4);
  char* z0 = p;  // ---- zero-initialized region ----
  int*   cnt   = (int*)carve((size_t)N * 4);
  int*   fill  = (int*)carve((size_t)N * 4);
  float* sums1 = (float*)carve(256 * 4);
  float* sums2 = (float*)carve(256 * 4);
  float* gsum  = (float*)carve((size_t)G * 4);
  int*   gcnt  = (int*)carve((size_t)G * 4);
  int*   bsums = (int*)carve(256 * 4);
  size_t zbytes = (size_t)(p - z0);

  hipMemsetAsync(z0, 0, zbytes, stream);

  // CSR build (shared by both conv layers)
  k_hist_dst<<<1024, 256, 0, stream>>>(dst, cnt, E);
  k_dinv<<<(N + 255) / 256, 256, 0, stream>>>(cnt, dinv, N);
  int nb = (N + 2047) / 2048;
  k_scan1<<<nb, 256, 0, stream>>>(cnt, rowptr, bsums, N);
  k_scan2<<<1, 256, 0, stream>>>(bsums, nb);
  k_scan3<<<(N + 1 + 255) / 256, 256, 0, stream>>>(rowptr, bsums, N, E);
  k_scatter<<<1024, 256, 0, stream>>>(src, dst, rowptr, fill, colidx, E);

  int gblocks = (N + 127) / 128;
  int ablocks = (N + 3) / 4;
  // layer 1
  k_gemm<<<gblocks, 512, 0, stream>>>(x, W1, bufY, N, dinv, nullptr, nullptr);
  k_aggregate<<<ablocks, 256, 0, stream>>>(bufY, rowptr, colidx, dinv, bufAgg, N);
  k_colstats<<<512, 256, 0, stream>>>(bufAgg, N, sums1);
  k_bnparams<<<1, 128, 0, stream>>>(sums1, 1.0f / (float)N, gamma1, beta1, scale1, shift1);
  // layer 2 (BN1+ReLU fused into GEMM2 input staging)
  k_gemm<<<gblocks, 512, 0, stream>>>(bufAgg, W2, bufY, N, dinv, scale1, shift1);
  k_aggregate<<<ablocks, 256, 0, stream>>>(bufY, rowptr, colidx, dinv, bufAgg, N);
  k_colstats<<<512, 256, 0, stream>>>(bufAgg, N, sums2);
  k_bnparams<<<1, 128, 0, stream>>>(sums2, 1.0f / (float)N, gamma2, beta2, scale2, shift2);
  // pooling + output head (BN2+ReLU+proj fused, h2 never materialized)
  k_ghist<<<256, 256, 0, stream>>>(batch, gcnt, N);
  k_finalnode<<<ablocks, 256, 0, stream>>>(bufAgg, scale2, shift2, wout, batch, gsum, N);
  k_finalout<<<(G + 255) / 256, 256, 0, stream>>>(gsum, gcnt, bout, out, G);
}